// Round 1
// baseline (26.911 us; speedup 1.0000x reference)
//
#include <hip/hip_runtime.h>

// Depthwise causal FIR conv1d.
// x: (B, L, H, D) fp32, filters: (H, D, K) fp32, y: (B, L, H, D) fp32
// y[b,l,c] = sum_k filt[c,k] * x[b, l-6+k, c]   (zero-padded for l-6+k < 0)
// C = H*D = 1024 is the innermost contiguous pair -> vectorize over channels.

constexpr int B_ = 4;
constexpr int L_ = 4096;
constexpr int H_ = 16;
constexpr int D_ = 64;
constexpr int K_ = 7;
constexpr int C_ = H_ * D_;      // 1024
constexpr int C4_ = C_ / 4;      // 256 float4 channel-groups
constexpr int LCHUNK = 32;       // L rows per block
constexpr int NCHUNK = L_ / LCHUNK;  // 128

__global__ __launch_bounds__(256)
void dwfir_kernel(const float* __restrict__ x,
                  const float* __restrict__ filt,
                  float* __restrict__ y) {
    const int c4 = threadIdx.x;              // 0..255 -> channels 4*c4 .. 4*c4+3
    const int chunk = blockIdx.x;            // 0 .. B_*NCHUNK-1
    const int b  = chunk / NCHUNK;
    const int l0 = (chunk % NCHUNK) * LCHUNK;

    // ---- load filters: 28 consecutive floats per thread (channel-major [c][k]),
    //      112 B per thread, 16B-aligned -> 7 float4 loads, then static unpack.
    const float4* fv = reinterpret_cast<const float4*>(filt) + c4 * 7;
    float ff[28];
    #pragma unroll
    for (int i = 0; i < 7; ++i) {
        float4 t = fv[i];
        ff[4 * i + 0] = t.x;
        ff[4 * i + 1] = t.y;
        ff[4 * i + 2] = t.z;
        ff[4 * i + 3] = t.w;
    }
    // ff[ch*7 + k] = filt[4*c4 + ch][k]

    const float4* xv = reinterpret_cast<const float4*>(x);
    float4*       yv = reinterpret_cast<float4*>(y);

    // ---- preload sliding window: w[j] = x[b, l0-6+j, :] for j=0..5
    float4 w[7];
    #pragma unroll
    for (int j = 0; j < 6; ++j) {
        const int l = l0 - 6 + j;
        if (l >= 0) {
            w[j] = xv[(size_t)(b * L_ + l) * C4_ + c4];
        } else {
            w[j] = make_float4(0.f, 0.f, 0.f, 0.f);
        }
    }

    // ---- main loop over the L-chunk; all indices static under full unroll
    #pragma unroll
    for (int i = 0; i < LCHUNK; ++i) {
        const int l = l0 + i;
        const size_t off = (size_t)(b * L_ + l) * C4_ + c4;
        w[6] = xv[off];

        float4 acc;
        acc.x = ff[0]  * w[0].x;
        acc.y = ff[7]  * w[0].y;
        acc.z = ff[14] * w[0].z;
        acc.w = ff[21] * w[0].w;
        #pragma unroll
        for (int k = 1; k < 7; ++k) {
            acc.x = fmaf(ff[k],      w[k].x, acc.x);
            acc.y = fmaf(ff[7 + k],  w[k].y, acc.y);
            acc.z = fmaf(ff[14 + k], w[k].z, acc.z);
            acc.w = fmaf(ff[21 + k], w[k].w, acc.w);
        }
        yv[off] = acc;

        // shift window (static indices -> pure register renames after unroll)
        #pragma unroll
        for (int j = 0; j < 6; ++j) w[j] = w[j + 1];
    }
}

extern "C" void kernel_launch(void* const* d_in, const int* in_sizes, int n_in,
                              void* d_out, int out_size, void* d_ws, size_t ws_size,
                              hipStream_t stream) {
    const float* x    = (const float*)d_in[0];
    const float* filt = (const float*)d_in[1];
    float*       y    = (float*)d_out;

    dim3 grid(B_ * NCHUNK);   // 512 blocks
    dim3 block(256);
    dwfir_kernel<<<grid, block, 0, stream>>>(x, filt, y);
}